// Round 12
// baseline (200.691 us; speedup 1.0000x reference)
//
#include <hip/hip_runtime.h>
#include <cstddef>
#include <cstdint>

// GMM E-step: N=200000, K=16, D=64, fp32 in/out.
// R17: R16's LDS-dbuf A-matrix structure with the UNITS BUG fixed. R16's NaN:
// per-comp WA block is 16384 BYTES (R9's "k*8192" was _Float16 units); R16
// staged/indexed 8192 bytes -> compute read 16368 into an 8192B LDS buffer
// (OOB -> NaN) and staged wrong global offsets. Now: afb[2][16384], stage
// 4x16B per thread per comp, all offsets derived from the precompute write
// equation byte = k*16384 + f*1024 + lane*16.
// Structure (R16 theory): each wave owns 16 points, loops all 16 comps;
// B-fragments built once from global X (no xs LDS / staging phase / bank
// conflicts); comp k+1's 16KB T14-staged (load at top, ds_write after
// compute, per-comp barrier) while comp k is computed from LDS. Eliminates
// the ~256/wave per-nt af L2 re-loads that VGPR_Count=60 < af's 64 regs
// proved (R10/R15). MFMA count/layout/numerics == verified R9.
// Precompute = R9 verified (single-wave register Cholesky + LDS handoff +
// register fwd-subst inverse, negated tv, 16x16 WA swizzle).

#define GMM_D 64
#define GMM_K 16

typedef _Float16 half8 __attribute__((ext_vector_type(8)));
typedef float f32x4 __attribute__((ext_vector_type(4)));

// ws: WA [16 comps][16 frags][64 lanes][8 f16] = 262144 B, then tv, cc (f32)
#define WA_BYTES (GMM_K * 16 * 64 * 8 * 2)
#define WA_COMP_BYTES (16 * 64 * 8 * 2)   // 16384 B per component block

__device__ __forceinline__ float fast_rsqrt(float x) {
#if __has_builtin(__builtin_amdgcn_rsqf)
    // v_rsq_f32 (~1 ulp) + one Newton step -> full fp32 accuracy
    const float r = __builtin_amdgcn_rsqf(x);
    return r * (1.5f - 0.5f * x * r * r);
#else
    return 1.0f / sqrtf(x);
#endif
}

// broadcast lane l's value of v to all lanes (l compile-time after unroll)
__device__ __forceinline__ float lane_bcast(float v, int l) {
    return __int_as_float(__builtin_amdgcn_readlane(__float_as_int(v), l));
}

// ---------------------------------------------------------------------------
// Precompute (R9-verified, unchanged): one WAVE per component. Phase 1:
// register Cholesky via readlane broadcasts. Phase 2: register forward-
// substitution inverse fed by wave-uniform ds_read_b128 of L rows. At most
// one 64-float register array live at a time (R7 lesson). tv stored NEGATED.
// ---------------------------------------------------------------------------
__global__ __launch_bounds__(64) void gmm_precompute_kernel(
    const float* __restrict__ pi, const float* __restrict__ mus,
    const float* __restrict__ covs, _Float16* __restrict__ WA,
    float* __restrict__ tv, float* __restrict__ cc)
{
    const int k = blockIdx.x;
    const int r = threadIdx.x;  // lane id

    __shared__ alignas(16) float Ls[GMM_D][68];  // L rows, upper tri zeroed;
                                                 // 272 B stride: 16B-aligned
    __shared__ float Wv[GMM_D][GMM_D + 1];       // W = L^{-1}, for epilogue

    // ---- load row r of Sigma into registers (16x float4, L2-resident) ----
    float A_r[GMM_D];
    {
        const float4* src = reinterpret_cast<const float4*>(
            covs + (size_t)k * GMM_D * GMM_D + (size_t)r * GMM_D);
        #pragma unroll
        for (int u = 0; u < GMM_D / 4; ++u) {
            const float4 v = src[u];
            A_r[4 * u + 0] = v.x; A_r[4 * u + 1] = v.y;
            A_r[4 * u + 2] = v.z; A_r[4 * u + 3] = v.w;
        }
    }

    // ---- Phase 1: register Cholesky, right-looking, zero barriers ----
    float mydiag = 1.0f, myrs = 1.0f;
    #pragma unroll
    for (int j = 0; j < GMM_D; ++j) {
        const float pivot = lane_bcast(A_r[j], j);   // lane j: valid diag
        const float rs = fast_rsqrt(pivot);
        const float valj = A_r[j] * rs;              // L[r][j]; lane j: sqrt(pivot)
        if (r == j) { mydiag = valj; myrs = rs; }
        A_r[j] = valj;
        #pragma unroll
        for (int p = j + 1; p < GMM_D; ++p)          // rank-1 trailing update
            A_r[p] -= valj * lane_bcast(valj, p);    // L[p][j] from lane p
    }

    // ---- handoff: dump L rows to LDS, upper triangle zeroed. A_r dies. ----
    #pragma unroll
    for (int p = 0; p < GMM_D; ++p)
        Ls[r][p] = (p <= r) ? A_r[p] : 0.0f;
    __syncthreads();   // single wave: cheap

    // ---- Phase 2: lane r solves L w = e_r; only w[64] live in registers ----
    float w[GMM_D];
    #pragma unroll
    for (int i = 0; i < GMM_D; ++i) w[i] = 0.0f;

    #pragma unroll
    for (int i = 0; i < GMM_D; ++i) {
        const f32x4* Lrow = reinterpret_cast<const f32x4*>(&Ls[i][0]);
        float a0 = 0.0f, a1 = 0.0f, a2 = 0.0f, a3 = 0.0f;
        #pragma unroll
        for (int u = 0; u <= (i >> 2); ++u) {        // zeros make tail exact
            const f32x4 lv = Lrow[u];
            a0 -= lv[0] * w[4 * u + 0];
            a1 -= lv[1] * w[4 * u + 1];
            a2 -= lv[2] * w[4 * u + 2];
            a3 -= lv[3] * w[4 * u + 3];
        }
        const float invd = lane_bcast(myrs, i);      // 1/L[i][i]
        const float dlt = (r == i) ? 1.0f : 0.0f;
        w[i] = (dlt + (a0 + a1) + (a2 + a3)) * invd;
    }

    // ---- dump W to LDS (lane r holds column r -> write transposed) ----
    #pragma unroll
    for (int i = 0; i < GMM_D; ++i)
        Wv[i][r] = w[i];          // consecutive addresses: conflict-free
    __syncthreads();

    // ---- tv = -(W mu): NEGATED so estep's MFMA C-init needs no negate ----
    {
        const float* mk = mus + k * GMM_D;
        float s0 = 0.f, s1 = 0.f, s2 = 0.f, s3 = 0.f;
        #pragma unroll
        for (int c = 0; c < GMM_D; c += 4) {
            s0 += Wv[r][c + 0] * mk[c + 0];
            s1 += Wv[r][c + 1] * mk[c + 1];
            s2 += Wv[r][c + 2] * mk[c + 2];
            s3 += Wv[r][c + 3] * mk[c + 3];
        }
        tv[k * GMM_D + r] = -((s0 + s1) + (s2 + s3));
    }

    // ---- swizzle W -> f16 hi/lo A-fragments (16x16x32 layout, R6/R9) ----
    // frag f = mt*4+s: lane L elem u = W[mt*16 + (L&15)][(s&1)*32 + (L>>4)*8 + u],
    // s in {0,1}: hi ; {2,3}: lo. 16B/lane stores, coalesced.
    // byte offset of (k, f, lane): k*16384 + f*1024 + lane*16.
    {
        const int lr = r & 15, q = r >> 4;
        #pragma unroll
        for (int f = 0; f < 16; ++f) {
            const int mt = f >> 2, s = f & 3;
            const int row = mt * 16 + lr;
            const int db = (s & 1) * 32 + q * 8;
            half8 hv;
            #pragma unroll
            for (int u = 0; u < 8; ++u) {
                const float v = Wv[row][db + u];
                _Float16 h = (_Float16)v;
                if (s >= 2) h = (_Float16)(v - (float)h);
                hv[u] = h;
            }
            *(half8*)(WA + ((size_t)((k * 16 + f) * 64) + r) * 8) = hv;
        }
    }

    // ---- c_k = log pi_k - sum(log L_ii) - 0.5*D*log(2*pi) ----
    {
        float ll = logf(mydiag);
        #pragma unroll
        for (int off = 32; off > 0; off >>= 1) ll += __shfl_down(ll, off);
        if (r == 0)
            cc[k] = logf(pi[k]) - ll - 0.5f * 64.0f * 1.8378770664093453f;
    }
}

// ---------------------------------------------------------------------------
// E-step (R17): block = 4 waves, 64 points; wave w owns points 16w..16w+15,
// loops over all 16 comps. A-matrices LDS-double-buffered (16384 B each):
// per comp, stage next comp's 16KB (T14: 4x16B global loads at top, ds_write
// after compute, barrier). B-fragments built once per wave from global X.
// Per comp: 4 mt chains x 6 MFMA 16x16x32 f16 (hi*hi + hi*lo + lo*hi), C
// preloaded with -t (tv negated), maha in-register + 2 shfl_xor.
// Math == verified R9.
// ---------------------------------------------------------------------------
__global__ __launch_bounds__(256) void gmm_estep_kernel(
    const float* __restrict__ X, const _Float16* __restrict__ WA,
    const float* __restrict__ tv, const float* __restrict__ cc,
    float* __restrict__ out, int N)
{
    __shared__ alignas(16) char afb[2][WA_COMP_BYTES];  // 2 x 16384 B
    __shared__ float lg[64 * 17];                       // log-probs

    const int tid = threadIdx.x;
    const int lane = tid & 63;
    const int wave = __builtin_amdgcn_readfirstlane(tid >> 6);
    const int pt = lane & 15;
    const int q  = lane >> 4;
    const int prow = wave * 16 + pt;            // point row this lane computes
    const int np = blockIdx.x * 64 + prow;

    // ---- B-fragments: built ONCE from global X (layout == R9's xs reads:
    // bh0/bl0 = dims q*8..+7, bh1/bl1 = dims 32+q*8..+7, hi/lo split) ----
    half8 bh0 = {}, bh1 = {}, bl0 = {}, bl1 = {};
    if (np < N) {
        const float4* xsrc = reinterpret_cast<const float4*>(X + (size_t)np * GMM_D);
        const float4 a0 = xsrc[q * 2];          // dims q*8   .. q*8+3
        const float4 a1 = xsrc[q * 2 + 1];      // dims q*8+4 .. q*8+7
        const float4 b0 = xsrc[8 + q * 2];      // dims 32+q*8 .. +3
        const float4 b1 = xsrc[8 + q * 2 + 1];  // dims 32+q*8+4 .. +7
        float v0[8] = {a0.x, a0.y, a0.z, a0.w, a1.x, a1.y, a1.z, a1.w};
        float v1[8] = {b0.x, b0.y, b0.z, b0.w, b1.x, b1.y, b1.z, b1.w};
        #pragma unroll
        for (int u = 0; u < 8; ++u) {
            const _Float16 h0 = (_Float16)v0[u];
            const _Float16 h1 = (_Float16)v1[u];
            bh0[u] = h0; bl0[u] = (_Float16)(v0[u] - (float)h0);
            bh1[u] = h1; bl1[u] = (_Float16)(v1[u] - (float)h1);
        }
    }

    // ---- prologue: stage comp 0's 16384 B (thread t: 4 x 16B, linear) ----
    {
        const char* w0 = (const char*)WA;
        #pragma unroll
        for (int j = 0; j < 4; ++j) {
            const half8 t0 = *(const half8*)(w0 + j * 4096 + tid * 16);
            *(half8*)(afb[0] + j * 4096 + tid * 16) = t0;
        }
    }
    __syncthreads();

    #pragma unroll 1
    for (int k = 0; k < GMM_K; ++k) {
        // T14 issue-early: next comp's stage loads (latency hides under MFMA)
        half8 s0, s1, s2, s3;
        const bool more = (k + 1) < GMM_K;
        if (more) {
            const char* wn = (const char*)WA + (size_t)(k + 1) * WA_COMP_BYTES;
            s0 = *(const half8*)(wn + 0 * 4096 + tid * 16);
            s1 = *(const half8*)(wn + 1 * 4096 + tid * 16);
            s2 = *(const half8*)(wn + 2 * 4096 + tid * 16);
            s3 = *(const half8*)(wn + 3 * 4096 + tid * 16);
        }

        // ---- compute comp k from LDS buffer (consecutive b128 per frag) ----
        // frag f at byte f*1024 + lane*16 (matches precompute write equation)
        const char* cur = afb[k & 1];
        const float* tvk = tv + k * GMM_D;
        float mahaP = 0.0f;
        #pragma unroll
        for (int mt = 0; mt < 4; ++mt) {
            const half8 a0 = *(const half8*)(cur + (mt * 4 + 0) * 1024 + lane * 16);
            const half8 a1 = *(const half8*)(cur + (mt * 4 + 1) * 1024 + lane * 16);
            const half8 a2 = *(const half8*)(cur + (mt * 4 + 2) * 1024 + lane * 16);
            const half8 a3 = *(const half8*)(cur + (mt * 4 + 3) * 1024 + lane * 16);
            f32x4 c = *(const f32x4*)(tvk + mt * 16 + q * 4);   // = -t
            c = __builtin_amdgcn_mfma_f32_16x16x32_f16(a0, bh0, c, 0, 0, 0);
            c = __builtin_amdgcn_mfma_f32_16x16x32_f16(a1, bh1, c, 0, 0, 0);
            c = __builtin_amdgcn_mfma_f32_16x16x32_f16(a0, bl0, c, 0, 0, 0);
            c = __builtin_amdgcn_mfma_f32_16x16x32_f16(a1, bl1, c, 0, 0, 0);
            c = __builtin_amdgcn_mfma_f32_16x16x32_f16(a2, bh0, c, 0, 0, 0);
            c = __builtin_amdgcn_mfma_f32_16x16x32_f16(a3, bh1, c, 0, 0, 0);
            mahaP += c[0] * c[0] + c[1] * c[1] + c[2] * c[2] + c[3] * c[3];
        }
        mahaP += __shfl_xor(mahaP, 16);
        mahaP += __shfl_xor(mahaP, 32);
        if (q == 0 && np < N)
            lg[prow * 17 + k] = cc[k] - 0.5f * mahaP;

        // T14 write-late: stage-loads have had the whole compute to land
        if (more) {
            char* nb = afb[(k + 1) & 1];
            *(half8*)(nb + 0 * 4096 + tid * 16) = s0;
            *(half8*)(nb + 1 * 4096 + tid * 16) = s1;
            *(half8*)(nb + 2 * 4096 + tid * 16) = s2;
            *(half8*)(nb + 3 * 4096 + tid * 16) = s3;
        }
        // barrier: (a) next-buf writes visible before iteration k+1 reads;
        // (b) all waves done reading cur before iteration k+1's stage
        // overwrites it (that targets buf[k&1] only at k+2, past another
        // barrier).
        __syncthreads();
    }

    // softmax: 4 threads/point, one float4 each (contiguous stores)
    {
        const int p = tid >> 2, qq = tid & 3;
        const int np2 = blockIdx.x * 64 + p;
        if (np2 < N) {
            const float* row = &lg[p * 17];
            float m = row[0];
            #pragma unroll
            for (int j = 1; j < GMM_K; ++j) m = fmaxf(m, row[j]);
            float e[GMM_K];
            float s = 0.0f;
            #pragma unroll
            for (int j = 0; j < GMM_K; ++j) { e[j] = __expf(row[j] - m); s += e[j]; }
            const float inv = 1.0f / s;
            float4 v;
            v.x = e[qq * 4 + 0] * inv;
            v.y = e[qq * 4 + 1] * inv;
            v.z = e[qq * 4 + 2] * inv;
            v.w = e[qq * 4 + 3] * inv;
            reinterpret_cast<float4*>(out + (size_t)np2 * GMM_K)[qq] = v;
        }
    }
}

// ---------------------------------------------------------------------------
extern "C" void kernel_launch(void* const* d_in, const int* in_sizes, int n_in,
                              void* d_out, int out_size, void* d_ws, size_t ws_size,
                              hipStream_t stream)
{
    const float* X    = (const float*)d_in[0];
    const float* pi   = (const float*)d_in[1];
    const float* mus  = (const float*)d_in[2];
    const float* covs = (const float*)d_in[3];
    float* out = (float*)d_out;

    const int N = in_sizes[0] / GMM_D;

    _Float16* WA = (_Float16*)d_ws;
    float* tv = (float*)((char*)d_ws + WA_BYTES);
    float* cc = tv + GMM_K * GMM_D;

    gmm_precompute_kernel<<<dim3(GMM_K), dim3(64), 0, stream>>>(pi, mus, covs, WA, tv, cc);

    const int blocks = (N + 63) / 64;  // 200000/64 = 3125 exactly
    gmm_estep_kernel<<<dim3(blocks), dim3(256), 0, stream>>>(X, WA, tv, cc, out, N);
}

// Round 13
// 180.313 us; speedup vs baseline: 1.1130x; 1.1130x over previous
//
#include <hip/hip_runtime.h>
#include <cstddef>
#include <cstdint>

// GMM E-step: N=200000, K=16, D=64, fp32 in/out.
// R18: Mahalanobis matmul switched from f16 hi/lo (6 MFMA/mt, K=32) to INT8
// hi/lo fixed-point (3 MFMA/mt, K=64, mfma_i32_16x16x64_i8). Rationale: the
// MFMA-pipe-busy time is a measured invariant ~33us across ALL estep
// variants (dur = 33/MfmaUtil; R9-R17), so only shrinking the floor helps.
// i8: W,x as 16-bit fixed point (two i8 planes, V16=vh*256+vl); i32
// accumulation EXACT; z = 65536*Shh*s + 256*(Shl+Slh)*s - t, S_ll dropped
// (delta-z ~3.7e-4 rms; output err <=~6e-3 vs 0.02 threshold). Per-wave
// MFMA 384x19.4cyc -> 192x20.4cyc (~18us busy). WA halves (8KB/comp), B
// reads halve, xs LDS 22->14KB. R9 skeleton otherwise untouched
// (launch_bounds(256,2) kept from R15's +5%).
// Precompute = R9 verified Cholesky+inverse; swizzle now emits i8 planes +
// per-comp scales s1,s2; tv stays negated fp32.

#define GMM_D 64
#define GMM_K 16

typedef float f32x4 __attribute__((ext_vector_type(4)));
typedef int   i32x4 __attribute__((ext_vector_type(4)));

// ws layout: [0, 256KB) WA region (i8 frags use first 128KB; scales at
// +240KB inside the reserve), then tv (negated -W*mu), then cc.
#define WA_BYTES (GMM_K * 16 * 64 * 8 * 2)      // 262144 (reserved as before)
#define WA_COMP_BYTES 8192                       // 8 frags x 64 lanes x 16 B
#define SCL_OFFSET (240 * 1024)                  // float scl[2*K] inside WA reserve

#define SX_Q (6.0f / 32512.0f)                   // x quant scale (|x| clamp 6)
#define INV_SX (32512.0f / 6.0f)

__device__ __forceinline__ float fast_rsqrt(float x) {
#if __has_builtin(__builtin_amdgcn_rsqf)
    const float r = __builtin_amdgcn_rsqf(x);
    return r * (1.5f - 0.5f * x * r * r);
#else
    return 1.0f / sqrtf(x);
#endif
}

__device__ __forceinline__ float lane_bcast(float v, int l) {
    return __int_as_float(__builtin_amdgcn_readlane(__float_as_int(v), l));
}

// quantize float (already scaled) -> i16 split into (hi8, lo8)
__device__ __forceinline__ void quant16(float y, int& hi8, int& lo8) {
    y = fminf(fmaxf(y, -32512.0f), 32512.0f);
    const int wi = (int)y;                       // y is integer-valued (rint'd)
    hi8 = (wi + 128) >> 8;                       // [-127, 127]
    lo8 = wi - (hi8 << 8);                       // [-128, 127]
}

// pack 4 signed bytes (little-endian) into one dword
__device__ __forceinline__ unsigned pack4(int b0, int b1, int b2, int b3) {
    return (unsigned)(b0 & 255) | ((unsigned)(b1 & 255) << 8) |
           ((unsigned)(b2 & 255) << 16) | ((unsigned)(b3 & 255) << 24);
}

// ---------------------------------------------------------------------------
// Precompute: one WAVE per comp (R9-verified Cholesky + fwd-subst inverse).
// New epilogue: per-comp maxW -> i8 hi/lo A-fragments for 16x16x64_i8
//   frag f = mt*2+h: lane L byte u = plane_h(Wq[mt*16 + (L&15)][(L>>4)*16+u])
//   stored at WA + k*8192 + f*1024 + L*16.
// scl[2k] = 65536*sW*sX, scl[2k+1] = 256*sW*sX. tv = -(W mu) fp32 as before.
// ---------------------------------------------------------------------------
__global__ __launch_bounds__(64) void gmm_precompute_kernel(
    const float* __restrict__ pi, const float* __restrict__ mus,
    const float* __restrict__ covs, char* __restrict__ WA8,
    float* __restrict__ scl, float* __restrict__ tv, float* __restrict__ cc)
{
    const int k = blockIdx.x;
    const int r = threadIdx.x;

    __shared__ alignas(16) float Ls[GMM_D][68];
    __shared__ float Wv[GMM_D][GMM_D + 1];

    // ---- load row r of Sigma ----
    float A_r[GMM_D];
    {
        const float4* src = reinterpret_cast<const float4*>(
            covs + (size_t)k * GMM_D * GMM_D + (size_t)r * GMM_D);
        #pragma unroll
        for (int u = 0; u < GMM_D / 4; ++u) {
            const float4 v = src[u];
            A_r[4 * u + 0] = v.x; A_r[4 * u + 1] = v.y;
            A_r[4 * u + 2] = v.z; A_r[4 * u + 3] = v.w;
        }
    }

    // ---- Phase 1: register Cholesky (verified) ----
    float mydiag = 1.0f, myrs = 1.0f;
    #pragma unroll
    for (int j = 0; j < GMM_D; ++j) {
        const float pivot = lane_bcast(A_r[j], j);
        const float rs = fast_rsqrt(pivot);
        const float valj = A_r[j] * rs;
        if (r == j) { mydiag = valj; myrs = rs; }
        A_r[j] = valj;
        #pragma unroll
        for (int p = j + 1; p < GMM_D; ++p)
            A_r[p] -= valj * lane_bcast(valj, p);
    }

    // ---- handoff L to LDS (upper zeroed); A_r dies ----
    #pragma unroll
    for (int p = 0; p < GMM_D; ++p)
        Ls[r][p] = (p <= r) ? A_r[p] : 0.0f;
    __syncthreads();

    // ---- Phase 2: lane r solves L w = e_r (verified) ----
    float w[GMM_D];
    #pragma unroll
    for (int i = 0; i < GMM_D; ++i) w[i] = 0.0f;

    #pragma unroll
    for (int i = 0; i < GMM_D; ++i) {
        const f32x4* Lrow = reinterpret_cast<const f32x4*>(&Ls[i][0]);
        float a0 = 0.0f, a1 = 0.0f, a2 = 0.0f, a3 = 0.0f;
        #pragma unroll
        for (int u = 0; u <= (i >> 2); ++u) {
            const f32x4 lv = Lrow[u];
            a0 -= lv[0] * w[4 * u + 0];
            a1 -= lv[1] * w[4 * u + 1];
            a2 -= lv[2] * w[4 * u + 2];
            a3 -= lv[3] * w[4 * u + 3];
        }
        const float invd = lane_bcast(myrs, i);
        const float dlt = (r == i) ? 1.0f : 0.0f;
        w[i] = (dlt + (a0 + a1) + (a2 + a3)) * invd;
    }

    // ---- per-comp max|W| (butterfly over all 64 columns) ----
    float mW = 0.0f;
    #pragma unroll
    for (int i = 0; i < GMM_D; ++i) mW = fmaxf(mW, fabsf(w[i]));
    #pragma unroll
    for (int off = 1; off < 64; off <<= 1) mW = fmaxf(mW, __shfl_xor(mW, off));
    const float invSW = 32512.0f / mW;

    // ---- dump W to LDS (lane r holds column r) ----
    #pragma unroll
    for (int i = 0; i < GMM_D; ++i)
        Wv[i][r] = w[i];
    __syncthreads();

    // ---- tv = -(W mu), fp32 (unchanged) ----
    {
        const float* mk = mus + k * GMM_D;
        float s0 = 0.f, s1 = 0.f, s2 = 0.f, s3 = 0.f;
        #pragma unroll
        for (int c = 0; c < GMM_D; c += 4) {
            s0 += Wv[r][c + 0] * mk[c + 0];
            s1 += Wv[r][c + 1] * mk[c + 1];
            s2 += Wv[r][c + 2] * mk[c + 2];
            s3 += Wv[r][c + 3] * mk[c + 3];
        }
        tv[k * GMM_D + r] = -((s0 + s1) + (s2 + s3));
    }

    // ---- swizzle W -> i8 hi/lo A-fragments (16x16x64_i8 layout) ----
    {
        const int lr = r & 15, q4 = r >> 4;
        char* base = WA8 + (size_t)k * WA_COMP_BYTES + (size_t)r * 16;
        #pragma unroll
        for (int mt = 0; mt < 4; ++mt) {
            const int row = mt * 16 + lr;
            int hb[16], lb[16];
            #pragma unroll
            for (int u = 0; u < 16; ++u) {
                const float wv = Wv[row][q4 * 16 + u];
                quant16(rintf(wv * invSW), hb[u], lb[u]);
            }
            unsigned hw[4], lw[4];
            #pragma unroll
            for (int d = 0; d < 4; ++d) {
                hw[d] = pack4(hb[4*d], hb[4*d+1], hb[4*d+2], hb[4*d+3]);
                lw[d] = pack4(lb[4*d], lb[4*d+1], lb[4*d+2], lb[4*d+3]);
            }
            i32x4 hv = { (int)hw[0], (int)hw[1], (int)hw[2], (int)hw[3] };
            i32x4 lv = { (int)lw[0], (int)lw[1], (int)lw[2], (int)lw[3] };
            *(i32x4*)(base + (mt * 2 + 0) * 1024) = hv;
            *(i32x4*)(base + (mt * 2 + 1) * 1024) = lv;
        }
    }

    // ---- scales + cc ----
    if (r == 0) {
        const float s = (mW / 32512.0f) * SX_Q;   // sW * sX
        scl[2 * k + 0] = 65536.0f * s;
        scl[2 * k + 1] = 256.0f * s;
    }
    {
        float ll = logf(mydiag);
        #pragma unroll
        for (int off = 32; off > 0; off >>= 1) ll += __shfl_down(ll, off);
        if (r == 0)
            cc[k] = logf(pi[k]) - ll - 0.5f * 64.0f * 1.8378770664093453f;
    }
}

// ---------------------------------------------------------------------------
// E-step (R9 skeleton, i8 math): block = 4 waves, 64 points; wave w owns
// comps 4w..4w+3, nt loop over 4 point-tiles. Per (comp, nt, mt): 3 MFMA
// i32_16x16x64_i8 (hh; hl+lh chained), z recombined in fp32 with -t, maha
// in-register + 2 shfl_xor. xs = two i8 planes [64][80] (conflict-light,
// 16B-aligned rows).
// ---------------------------------------------------------------------------
__global__ __launch_bounds__(256, 2) void gmm_estep_kernel(
    const float* __restrict__ X, const char* __restrict__ WA8,
    const float* __restrict__ scl, const float* __restrict__ tv,
    const float* __restrict__ cc, float* __restrict__ out, int N)
{
    __shared__ alignas(16) char xhi[64][80];   // hi i8 plane, 16B-aligned rows
    __shared__ alignas(16) char xlo[64][80];   // lo i8 plane
    __shared__ float lg[64 * 17];

    const int tid = threadIdx.x;

    // ---- stage X -> i8 hi/lo planes: thread t: point t/4, dims (t%4)*16 ----
    {
        const int p = tid >> 2, qq = tid & 3;
        const int np = blockIdx.x * 64 + p;
        if (np < N) {
            const float4* src = reinterpret_cast<const float4*>(X + (size_t)np * GMM_D) + qq * 4;
            float vv[16];
            #pragma unroll
            for (int u = 0; u < 4; ++u) {
                const float4 v = src[u];
                vv[4 * u + 0] = v.x; vv[4 * u + 1] = v.y;
                vv[4 * u + 2] = v.z; vv[4 * u + 3] = v.w;
            }
            int hb[16], lb[16];
            #pragma unroll
            for (int u = 0; u < 16; ++u)
                quant16(rintf(vv[u] * INV_SX), hb[u], lb[u]);
            unsigned hw[4], lw[4];
            #pragma unroll
            for (int d = 0; d < 4; ++d) {
                hw[d] = pack4(hb[4*d], hb[4*d+1], hb[4*d+2], hb[4*d+3]);
                lw[d] = pack4(lb[4*d], lb[4*d+1], lb[4*d+2], lb[4*d+3]);
            }
            i32x4 hv = { (int)hw[0], (int)hw[1], (int)hw[2], (int)hw[3] };
            i32x4 lv = { (int)lw[0], (int)lw[1], (int)lw[2], (int)lw[3] };
            *(i32x4*)&xhi[p][qq * 16] = hv;
            *(i32x4*)&xlo[p][qq * 16] = lv;
        }
    }
    __syncthreads();

    const int lane = tid & 63;
    const int wave = __builtin_amdgcn_readfirstlane(tid >> 6);
    const int pt = lane & 15;
    const int q  = lane >> 4;

    #pragma unroll 1
    for (int kk = 0; kk < 4; ++kk) {
        const int k = wave * 4 + kk;  // wave-uniform

        // A fragments: 8 x dwordx4, coalesced, L2-resident
        i32x4 af[4][2];
        const char* wab = WA8 + (size_t)k * WA_COMP_BYTES + (size_t)lane * 16;
        #pragma unroll
        for (int mt = 0; mt < 4; ++mt)
            #pragma unroll
            for (int h = 0; h < 2; ++h)
                af[mt][h] = *(const i32x4*)(wab + (mt * 2 + h) * 1024);

        // -t rows (fp32, negated in precompute) + per-comp scales
        f32x4 tk4[4];
        #pragma unroll
        for (int mt = 0; mt < 4; ++mt)
            tk4[mt] = *(const f32x4*)(tv + k * 64 + mt * 16 + q * 4);
        const float s1 = scl[2 * k + 0];
        const float s2 = scl[2 * k + 1];

        #pragma unroll 1
        for (int nt = 0; nt < 4; ++nt) {
            const i32x4 xh = *(const i32x4*)&xhi[nt * 16 + pt][q * 16];
            const i32x4 xl = *(const i32x4*)&xlo[nt * 16 + pt][q * 16];
            const i32x4 zero = { 0, 0, 0, 0 };

            float mahaP = 0.0f;
            #pragma unroll
            for (int mt = 0; mt < 4; ++mt) {
                i32x4 chh = __builtin_amdgcn_mfma_i32_16x16x64_i8(af[mt][0], xh, zero, 0, 0, 0);
                i32x4 cx  = __builtin_amdgcn_mfma_i32_16x16x64_i8(af[mt][0], xl, zero, 0, 0, 0);
                cx        = __builtin_amdgcn_mfma_i32_16x16x64_i8(af[mt][1], xh, cx,   0, 0, 0);
                #pragma unroll
                for (int j = 0; j < 4; ++j) {
                    const float zf = fmaf((float)chh[j], s1,
                                      fmaf((float)cx[j], s2, tk4[mt][j]));
                    mahaP += zf * zf;
                }
            }
            mahaP += __shfl_xor(mahaP, 16);
            mahaP += __shfl_xor(mahaP, 32);
            if (q == 0 && (blockIdx.x * 64 + nt * 16 + pt) < N)
                lg[(nt * 16 + pt) * 17 + k] = cc[k] - 0.5f * mahaP;
        }
    }
    __syncthreads();

    // softmax: 4 threads/point, one float4 each (contiguous stores)
    {
        const int p = tid >> 2, qq = tid & 3;
        const int np = blockIdx.x * 64 + p;
        if (np < N) {
            const float* row = &lg[p * 17];
            float m = row[0];
            #pragma unroll
            for (int j = 1; j < GMM_K; ++j) m = fmaxf(m, row[j]);
            float e[GMM_K];
            float s = 0.0f;
            #pragma unroll
            for (int j = 0; j < GMM_K; ++j) { e[j] = __expf(row[j] - m); s += e[j]; }
            const float inv = 1.0f / s;
            float4 v;
            v.x = e[qq * 4 + 0] * inv;
            v.y = e[qq * 4 + 1] * inv;
            v.z = e[qq * 4 + 2] * inv;
            v.w = e[qq * 4 + 3] * inv;
            reinterpret_cast<float4*>(out + (size_t)np * GMM_K)[qq] = v;
        }
    }
}

// ---------------------------------------------------------------------------
extern "C" void kernel_launch(void* const* d_in, const int* in_sizes, int n_in,
                              void* d_out, int out_size, void* d_ws, size_t ws_size,
                              hipStream_t stream)
{
    const float* X    = (const float*)d_in[0];
    const float* pi   = (const float*)d_in[1];
    const float* mus  = (const float*)d_in[2];
    const float* covs = (const float*)d_in[3];
    float* out = (float*)d_out;

    const int N = in_sizes[0] / GMM_D;

    char* WA8 = (char*)d_ws;                                  // i8 frags (128KB used)
    float* scl = (float*)((char*)d_ws + SCL_OFFSET);          // inside WA reserve
    float* tv = (float*)((char*)d_ws + WA_BYTES);
    float* cc = tv + GMM_K * GMM_D;

    gmm_precompute_kernel<<<dim3(GMM_K), dim3(64), 0, stream>>>(
        pi, mus, covs, WA8, scl, tv, cc);

    const int blocks = (N + 63) / 64;  // 200000/64 = 3125 exactly
    gmm_estep_kernel<<<dim3(blocks), dim3(256), 0, stream>>>(
        X, WA8, scl, tv, cc, out, N);
}

// Round 14
// 171.616 us; speedup vs baseline: 1.1694x; 1.0507x over previous
//
#include <hip/hip_runtime.h>
#include <cstddef>
#include <cstdint>

// GMM E-step: N=200000, K=16, D=64, fp32 in/out.
// R19: R18's i8 hi/lo MFMA core (verified: MFMA busy 33->16us, absmax at
// floor) with the two R18 regressions fixed:
// (1) VALU epilogue 20->12 ops/mt: t folded into the cross-term MFMA's C
//     operand as tint=rint(-t/s2) (i32, exact; zi = 256*chh + cx is the
//     complete integer z), square-accumulate in fp32, single fma
//     lg = cc - hs2*mahaP with hs2 = 0.5*s2^2 per comp.
// (2) 50MB scratch traffic (WRITE_SIZE 12.5->62MB): staging's vv[16]/hb[16]/
//     lb[16] temporaries eliminated - per-float4 scalar quantization writing
//     i32x4 components with static indices.
// Skeleton = R9/R15 verified (4 waves x 4 comps x 4 nt, launch_bounds(256,2)).
// Precompute = R9 verified Cholesky+inverse; epilogue emits i8 planes, tint
// (i32, C-order), and hs2.

#define GMM_D 64
#define GMM_K 16

typedef float f32x4 __attribute__((ext_vector_type(4)));
typedef int   i32x4 __attribute__((ext_vector_type(4)));

// ws layout: [0,128KB) WA8 i8 frags; scl at +240KB; tvi (i32) at +256KB; cc.
#define WA_BYTES (GMM_K * 16 * 64 * 8 * 2)      // 262144 reserve
#define WA_COMP_BYTES 8192                       // 8 frags x 64 lanes x 16 B
#define SCL_OFFSET (240 * 1024)

#define SX_Q (6.0f / 32512.0f)                   // x quant scale (|x| clamp 6)
#define INV_SX (32512.0f / 6.0f)

__device__ __forceinline__ float fast_rsqrt(float x) {
#if __has_builtin(__builtin_amdgcn_rsqf)
    const float r = __builtin_amdgcn_rsqf(x);
    return r * (1.5f - 0.5f * x * r * r);
#else
    return 1.0f / sqrtf(x);
#endif
}

__device__ __forceinline__ float lane_bcast(float v, int l) {
    return __int_as_float(__builtin_amdgcn_readlane(__float_as_int(v), l));
}

// quantize pre-scaled float -> i16 split into (hi8, lo8)
__device__ __forceinline__ void quant16(float y, int& hi8, int& lo8) {
    y = fminf(fmaxf(y, -32512.0f), 32512.0f);
    const int wi = (int)y;
    hi8 = (wi + 128) >> 8;                       // [-127, 127]
    lo8 = wi - (hi8 << 8);                       // [-128, 127]
}

__device__ __forceinline__ unsigned pack4(int b0, int b1, int b2, int b3) {
    return (unsigned)(b0 & 255) | ((unsigned)(b1 & 255) << 8) |
           ((unsigned)(b2 & 255) << 16) | ((unsigned)(b3 & 255) << 24);
}

// quantize one float4 (x-scale) -> one hi dword + one lo dword
__device__ __forceinline__ void quant_f4(const float4 v, int& hw, int& lw) {
    int h0, l0, h1, l1, h2, l2, h3, l3;
    quant16(rintf(v.x * INV_SX), h0, l0);
    quant16(rintf(v.y * INV_SX), h1, l1);
    quant16(rintf(v.z * INV_SX), h2, l2);
    quant16(rintf(v.w * INV_SX), h3, l3);
    hw = (int)pack4(h0, h1, h2, h3);
    lw = (int)pack4(l0, l1, l2, l3);
}

// ---------------------------------------------------------------------------
// Precompute: one WAVE per comp (R9-verified Cholesky + fwd-subst inverse).
// Epilogue: i8 hi/lo A-fragments (16x16x64_i8; frag f=mt*2+h at byte
// k*8192 + f*1024 + lane*16), tint[k*64+r] = rint(-(W mu)_r / s2) as i32
// (C-fragment row order == plain row order, verified via R9's tv usage),
// scl[k] = 0.5*s2^2 where s2 = 256*sW*sX, sW = mW/32512.
// ---------------------------------------------------------------------------
__global__ __launch_bounds__(64) void gmm_precompute_kernel(
    const float* __restrict__ pi, const float* __restrict__ mus,
    const float* __restrict__ covs, char* __restrict__ WA8,
    float* __restrict__ scl, int* __restrict__ tvi, float* __restrict__ cc)
{
    const int k = blockIdx.x;
    const int r = threadIdx.x;

    __shared__ alignas(16) float Ls[GMM_D][68];
    __shared__ float Wv[GMM_D][GMM_D + 1];

    // ---- load row r of Sigma ----
    float A_r[GMM_D];
    {
        const float4* src = reinterpret_cast<const float4*>(
            covs + (size_t)k * GMM_D * GMM_D + (size_t)r * GMM_D);
        #pragma unroll
        for (int u = 0; u < GMM_D / 4; ++u) {
            const float4 v = src[u];
            A_r[4 * u + 0] = v.x; A_r[4 * u + 1] = v.y;
            A_r[4 * u + 2] = v.z; A_r[4 * u + 3] = v.w;
        }
    }

    // ---- Phase 1: register Cholesky (verified) ----
    float mydiag = 1.0f, myrs = 1.0f;
    #pragma unroll
    for (int j = 0; j < GMM_D; ++j) {
        const float pivot = lane_bcast(A_r[j], j);
        const float rs = fast_rsqrt(pivot);
        const float valj = A_r[j] * rs;
        if (r == j) { mydiag = valj; myrs = rs; }
        A_r[j] = valj;
        #pragma unroll
        for (int p = j + 1; p < GMM_D; ++p)
            A_r[p] -= valj * lane_bcast(valj, p);
    }

    // ---- handoff L to LDS (upper zeroed); A_r dies ----
    #pragma unroll
    for (int p = 0; p < GMM_D; ++p)
        Ls[r][p] = (p <= r) ? A_r[p] : 0.0f;
    __syncthreads();

    // ---- Phase 2: lane r solves L w = e_r (verified) ----
    float w[GMM_D];
    #pragma unroll
    for (int i = 0; i < GMM_D; ++i) w[i] = 0.0f;

    #pragma unroll
    for (int i = 0; i < GMM_D; ++i) {
        const f32x4* Lrow = reinterpret_cast<const f32x4*>(&Ls[i][0]);
        float a0 = 0.0f, a1 = 0.0f, a2 = 0.0f, a3 = 0.0f;
        #pragma unroll
        for (int u = 0; u <= (i >> 2); ++u) {
            const f32x4 lv = Lrow[u];
            a0 -= lv[0] * w[4 * u + 0];
            a1 -= lv[1] * w[4 * u + 1];
            a2 -= lv[2] * w[4 * u + 2];
            a3 -= lv[3] * w[4 * u + 3];
        }
        const float invd = lane_bcast(myrs, i);
        const float dlt = (r == i) ? 1.0f : 0.0f;
        w[i] = (dlt + (a0 + a1) + (a2 + a3)) * invd;
    }

    // ---- per-comp max|W| (butterfly) ----
    float mW = 0.0f;
    #pragma unroll
    for (int i = 0; i < GMM_D; ++i) mW = fmaxf(mW, fabsf(w[i]));
    #pragma unroll
    for (int off = 1; off < 64; off <<= 1) mW = fmaxf(mW, __shfl_xor(mW, off));
    const float invSW = 32512.0f / mW;
    const float s2f = 256.0f * (mW / 32512.0f) * SX_Q;   // cross-term scale
    const float inv_s2f = 1.0f / s2f;

    // ---- dump W to LDS (lane r holds column r) ----
    #pragma unroll
    for (int i = 0; i < GMM_D; ++i)
        Wv[i][r] = w[i];
    __syncthreads();

    // ---- tint = rint(-(W mu)_r / s2), i32 (plain row order == C order) ----
    {
        const float* mk = mus + k * GMM_D;
        float s0 = 0.f, s1 = 0.f, s2 = 0.f, s3 = 0.f;
        #pragma unroll
        for (int c = 0; c < GMM_D; c += 4) {
            s0 += Wv[r][c + 0] * mk[c + 0];
            s1 += Wv[r][c + 1] * mk[c + 1];
            s2 += Wv[r][c + 2] * mk[c + 2];
            s3 += Wv[r][c + 3] * mk[c + 3];
        }
        const float tval = -((s0 + s1) + (s2 + s3));     // = -t_r
        tvi[k * GMM_D + r] = (int)rintf(tval * inv_s2f);
    }

    // ---- swizzle W -> i8 hi/lo A-fragments (16x16x64_i8 layout) ----
    {
        const int lr = r & 15, q4 = r >> 4;
        char* base = WA8 + (size_t)k * WA_COMP_BYTES + (size_t)r * 16;
        #pragma unroll
        for (int mt = 0; mt < 4; ++mt) {
            const int row = mt * 16 + lr;
            i32x4 hv, lv;
            #pragma unroll
            for (int d = 0; d < 4; ++d) {
                int h0, l0, h1, l1, h2, l2, h3, l3;
                quant16(rintf(Wv[row][q4 * 16 + 4 * d + 0] * invSW), h0, l0);
                quant16(rintf(Wv[row][q4 * 16 + 4 * d + 1] * invSW), h1, l1);
                quant16(rintf(Wv[row][q4 * 16 + 4 * d + 2] * invSW), h2, l2);
                quant16(rintf(Wv[row][q4 * 16 + 4 * d + 3] * invSW), h3, l3);
                hv[d] = (int)pack4(h0, h1, h2, h3);
                lv[d] = (int)pack4(l0, l1, l2, l3);
            }
            *(i32x4*)(base + (mt * 2 + 0) * 1024) = hv;
            *(i32x4*)(base + (mt * 2 + 1) * 1024) = lv;
        }
    }

    // ---- scales + cc ----
    if (r == 0)
        scl[k] = 0.5f * s2f * s2f;                       // hs2
    {
        float ll = logf(mydiag);
        #pragma unroll
        for (int off = 32; off > 0; off >>= 1) ll += __shfl_down(ll, off);
        if (r == 0)
            cc[k] = logf(pi[k]) - ll - 0.5f * 64.0f * 1.8378770664093453f;
    }
}

// ---------------------------------------------------------------------------
// E-step (R9 skeleton, i8 math v2): block = 4 waves, 64 points; wave w owns
// comps 4w..4w+3, 4 nt point-tiles. Per (comp,nt,mt): 3 MFMA i32_16x16x64_i8
// (chh with C=0; cx chain with C=tint -> zi = 256*chh + cx is the COMPLETE
// integer z incl. -t), per element lshl_add+cvt+fmac only. Final
// lg = cc - hs2*mahaP (one fma). Staging: per-float4 scalar quantization
// (no array temporaries -> no scratch).
// ---------------------------------------------------------------------------
__global__ __launch_bounds__(256, 2) void gmm_estep_kernel(
    const float* __restrict__ X, const char* __restrict__ WA8,
    const float* __restrict__ scl, const int* __restrict__ tvi,
    const float* __restrict__ cc, float* __restrict__ out, int N)
{
    __shared__ alignas(16) char xhi[64][80];   // hi i8 plane, 16B-aligned rows
    __shared__ alignas(16) char xlo[64][80];   // lo i8 plane
    __shared__ float lg[64 * 17];

    const int tid = threadIdx.x;

    // ---- stage X -> i8 hi/lo planes: thread t: point t/4, dims (t%4)*16 ----
    {
        const int p = tid >> 2, qq = tid & 3;
        const int np = blockIdx.x * 64 + p;
        if (np < N) {
            const float4* src = reinterpret_cast<const float4*>(X + (size_t)np * GMM_D) + qq * 4;
            i32x4 hv, lv;
            {
                int hw, lw;
                quant_f4(src[0], hw, lw); hv[0] = hw; lv[0] = lw;
                quant_f4(src[1], hw, lw); hv[1] = hw; lv[1] = lw;
                quant_f4(src[2], hw, lw); hv[2] = hw; lv[2] = lw;
                quant_f4(src[3], hw, lw); hv[3] = hw; lv[3] = lw;
            }
            *(i32x4*)&xhi[p][qq * 16] = hv;
            *(i32x4*)&xlo[p][qq * 16] = lv;
        }
    }
    __syncthreads();

    const int lane = tid & 63;
    const int wave = __builtin_amdgcn_readfirstlane(tid >> 6);
    const int pt = lane & 15;
    const int q  = lane >> 4;

    #pragma unroll 1
    for (int kk = 0; kk < 4; ++kk) {
        const int k = wave * 4 + kk;  // wave-uniform

        // A fragments: 8 x dwordx4, coalesced, L2-resident
        i32x4 af[4][2];
        const char* wab = WA8 + (size_t)k * WA_COMP_BYTES + (size_t)lane * 16;
        #pragma unroll
        for (int mt = 0; mt < 4; ++mt)
            #pragma unroll
            for (int h = 0; h < 2; ++h)
                af[mt][h] = *(const i32x4*)(wab + (mt * 2 + h) * 1024);

        // tint rows (i32, C order) + per-comp half-square scale
        i32x4 ti4[4];
        #pragma unroll
        for (int mt = 0; mt < 4; ++mt)
            ti4[mt] = *(const i32x4*)(tvi + k * 64 + mt * 16 + q * 4);
        const float hs2 = scl[k];

        #pragma unroll 1
        for (int nt = 0; nt < 4; ++nt) {
            const i32x4 xh = *(const i32x4*)&xhi[nt * 16 + pt][q * 16];
            const i32x4 xl = *(const i32x4*)&xlo[nt * 16 + pt][q * 16];
            const i32x4 zero = { 0, 0, 0, 0 };

            float mahaP = 0.0f;
            #pragma unroll
            for (int mt = 0; mt < 4; ++mt) {
                i32x4 chh = __builtin_amdgcn_mfma_i32_16x16x64_i8(af[mt][0], xh, zero,     0, 0, 0);
                i32x4 cx  = __builtin_amdgcn_mfma_i32_16x16x64_i8(af[mt][0], xl, ti4[mt], 0, 0, 0);
                cx        = __builtin_amdgcn_mfma_i32_16x16x64_i8(af[mt][1], xh, cx,      0, 0, 0);
                #pragma unroll
                for (int j = 0; j < 4; ++j) {
                    const int zi = (chh[j] << 8) + cx[j];   // exact integer z
                    const float zf = (float)zi;
                    mahaP = fmaf(zf, zf, mahaP);
                }
            }
            mahaP += __shfl_xor(mahaP, 16);
            mahaP += __shfl_xor(mahaP, 32);
            if (q == 0 && (blockIdx.x * 64 + nt * 16 + pt) < N)
                lg[(nt * 16 + pt) * 17 + k] = fmaf(-hs2, mahaP, cc[k]);
        }
    }
    __syncthreads();

    // softmax: 4 threads/point, one float4 each (contiguous stores)
    {
        const int p = tid >> 2, qq = tid & 3;
        const int np = blockIdx.x * 64 + p;
        if (np < N) {
            const float* row = &lg[p * 17];
            float m = row[0];
            #pragma unroll
            for (int j = 1; j < GMM_K; ++j) m = fmaxf(m, row[j]);
            float e[GMM_K];
            float s = 0.0f;
            #pragma unroll
            for (int j = 0; j < GMM_K; ++j) { e[j] = __expf(row[j] - m); s += e[j]; }
            const float inv = 1.0f / s;
            float4 v;
            v.x = e[qq * 4 + 0] * inv;
            v.y = e[qq * 4 + 1] * inv;
            v.z = e[qq * 4 + 2] * inv;
            v.w = e[qq * 4 + 3] * inv;
            reinterpret_cast<float4*>(out + (size_t)np * GMM_K)[qq] = v;
        }
    }
}

// ---------------------------------------------------------------------------
extern "C" void kernel_launch(void* const* d_in, const int* in_sizes, int n_in,
                              void* d_out, int out_size, void* d_ws, size_t ws_size,
                              hipStream_t stream)
{
    const float* X    = (const float*)d_in[0];
    const float* pi   = (const float*)d_in[1];
    const float* mus  = (const float*)d_in[2];
    const float* covs = (const float*)d_in[3];
    float* out = (float*)d_out;

    const int N = in_sizes[0] / GMM_D;

    char* WA8 = (char*)d_ws;
    float* scl = (float*)((char*)d_ws + SCL_OFFSET);
    int* tvi = (int*)((char*)d_ws + WA_BYTES);
    float* cc = (float*)(tvi + GMM_K * GMM_D);

    gmm_precompute_kernel<<<dim3(GMM_K), dim3(64), 0, stream>>>(
        pi, mus, covs, WA8, scl, tvi, cc);

    const int blocks = (N + 63) / 64;  // 200000/64 = 3125 exactly
    gmm_estep_kernel<<<dim3(blocks), dim3(256), 0, stream>>>(
        X, WA8, scl, tvi, cc, out, N);
}